// Round 1
// baseline (97.609 us; speedup 1.0000x reference)
//
#include <hip/hip_runtime.h>
#include <stdint.h>

#define N_PIX 4096
#define NB 8

typedef __attribute__((ext_vector_type(8))) short short8;
typedef __attribute__((ext_vector_type(4))) float f32x4;

#define SCL 0.18033688011112042f   // log2(e)/8
#define LOG2E 1.4426950408889634f

__device__ __forceinline__ short f2bf(float x){
  union { float f; uint32_t u; } a; a.f = x;
  uint32_t r = a.u + 0x7FFFu + ((a.u >> 16) & 1u);
  return (short)(r >> 16);
}
__device__ __forceinline__ float bf2f(short h){
  union { uint32_t u; float f; } a; a.u = ((uint32_t)(uint16_t)h) << 16; return a.f;
}
__device__ __forceinline__ float wredSum(float v){
  #pragma unroll
  for (int m = 1; m < 64; m <<= 1) v += __shfl_xor(v, m);
  return v;
}
__device__ __forceinline__ float wredMax(float v){
  #pragma unroll
  for (int m = 1; m < 64; m <<= 1) v = fmaxf(v, __shfl_xor(v, m));
  return v;
}

// ---------------- K0a: per-(b,c) spatial mean of x ----------------
__global__ __launch_bounds__(256) void k_xmean(const float* __restrict__ x, float* __restrict__ xm){
  int row = blockIdx.x;            // b*64 + c
  int tid = threadIdx.x;
  const float* xr = x + (size_t)row * N_PIX;
  float s = 0.f;
  #pragma unroll
  for (int i = 0; i < 16; i++) s += xr[tid + 256*i];
  s = wredSum(s);
  __shared__ float red[4];
  if ((tid & 63) == 0) red[tid >> 6] = s;
  __syncthreads();
  if (tid == 0) xm[row] = (red[0]+red[1]+red[2]+red[3]) * (1.0f / N_PIX);
}

// ---------------- K0b: qm = Wq xm + bq, km = Wk xm + bk ----------------
__global__ void k_means(const float* __restrict__ wq, const float* __restrict__ bq,
                        const float* __restrict__ wk, const float* __restrict__ bk,
                        const float* __restrict__ xm, float* __restrict__ qm, float* __restrict__ km){
  int b = blockIdx.x; int c = threadIdx.x;   // 64 threads
  float sq = 0.f, sk = 0.f;
  for (int cc = 0; cc < 64; cc++){
    float xv = xm[b*64 + cc];
    sq += wq[c*64 + cc] * xv;
    sk += wk[c*64 + cc] * xv;
  }
  qm[b*64 + c] = sq + bq[c];
  km[b*64 + c] = sk + bk[c];
}

// ---------------- K1: QKV 1x1-conv GEMM (MFMA) + whitening + unary logits ----------------
// Q: [B][N][64] bf16, whitened & pre-scaled by log2(e)/8
// K: [B][N][64] bf16, whitened (unscaled)
// V: [B][64][N] bf16
// u: [B][N] f32, u[n] = qm . (k[n]-km)
__global__ __launch_bounds__(256) void k_qkv(
    const float* __restrict__ x,
    const float* __restrict__ wq, const float* __restrict__ bq,
    const float* __restrict__ wk, const float* __restrict__ bk,
    const float* __restrict__ wv, const float* __restrict__ bv,
    const float* __restrict__ qm, const float* __restrict__ km,
    short* __restrict__ Q, short* __restrict__ K, short* __restrict__ V,
    float* __restrict__ u)
{
  int blk = blockIdx.x;
  int b  = blk >> 5;
  int n0 = (blk & 31) * 128;
  int tid = threadIdx.x;
  int w = tid >> 6, l = tid & 63, lr = l & 15, lg = l >> 4;
  const float* xb = x + (size_t)b * 64 * N_PIX;

  int ncol[2];
  ncol[0] = n0 + w*32 + lr;
  ncol[1] = ncol[0] + 16;

  // B-fragments from x (shared across the 3 matrices)
  short8 bx[2][2];
  #pragma unroll
  for (int tj = 0; tj < 2; tj++){
    #pragma unroll
    for (int kc = 0; kc < 2; kc++){
      short8 t;
      #pragma unroll
      for (int j = 0; j < 8; j++){
        int cp = kc*32 + lg*8 + j;
        t[j] = f2bf(xb[(size_t)cp * N_PIX + ncol[tj]]);
      }
      bx[tj][kc] = t;
    }
  }

  float qmv[4][4];
  #pragma unroll
  for (int ti = 0; ti < 4; ti++)
    #pragma unroll
    for (int r = 0; r < 4; r++)
      qmv[ti][r] = qm[b*64 + ti*16 + lg*4 + r];

  short* Qb = Q + (size_t)b * N_PIX * 64;
  short* Kb = K + (size_t)b * N_PIX * 64;
  short* Vb = V + (size_t)b * 64 * N_PIX;
  const f32x4 z4 = {0.f, 0.f, 0.f, 0.f};

  // ---------- Q ----------
  {
    short8 aw[4][2];
    #pragma unroll
    for (int ti = 0; ti < 4; ti++)
      #pragma unroll
      for (int kc = 0; kc < 2; kc++){
        const float* wr = wq + (ti*16 + lr)*64 + kc*32 + lg*8;
        short8 t;
        #pragma unroll
        for (int j = 0; j < 8; j++) t[j] = f2bf(wr[j]);
        aw[ti][kc] = t;
      }
    f32x4 acc[4][2];
    #pragma unroll
    for (int ti = 0; ti < 4; ti++)
      #pragma unroll
      for (int tj = 0; tj < 2; tj++){
        acc[ti][tj] = z4;
        #pragma unroll
        for (int kc = 0; kc < 2; kc++)
          acc[ti][tj] = __builtin_amdgcn_mfma_f32_16x16x32_bf16(aw[ti][kc], bx[tj][kc], acc[ti][tj], 0, 0, 0);
      }
    float adj[4][4];
    #pragma unroll
    for (int ti = 0; ti < 4; ti++)
      #pragma unroll
      for (int r = 0; r < 4; r++)
        adj[ti][r] = bq[ti*16 + lg*4 + r] - qmv[ti][r];
    #pragma unroll
    for (int ti = 0; ti < 4; ti++)
      #pragma unroll
      for (int tj = 0; tj < 2; tj++){
        float v0 = (acc[ti][tj][0] + adj[ti][0]) * SCL;
        float v1 = (acc[ti][tj][1] + adj[ti][1]) * SCL;
        float v2 = (acc[ti][tj][2] + adj[ti][2]) * SCL;
        float v3 = (acc[ti][tj][3] + adj[ti][3]) * SCL;
        uint32_t p0 = ((uint32_t)(uint16_t)f2bf(v1) << 16) | (uint16_t)f2bf(v0);
        uint32_t p1 = ((uint32_t)(uint16_t)f2bf(v3) << 16) | (uint16_t)f2bf(v2);
        uint32_t* qr = (uint32_t*)(Qb + (size_t)ncol[tj]*64);
        qr[ti*8 + lg*2]     = p0;
        qr[ti*8 + lg*2 + 1] = p1;
      }
  }

  // ---------- K (+ unary logits) ----------
  {
    short8 aw[4][2];
    #pragma unroll
    for (int ti = 0; ti < 4; ti++)
      #pragma unroll
      for (int kc = 0; kc < 2; kc++){
        const float* wr = wk + (ti*16 + lr)*64 + kc*32 + lg*8;
        short8 t;
        #pragma unroll
        for (int j = 0; j < 8; j++) t[j] = f2bf(wr[j]);
        aw[ti][kc] = t;
      }
    f32x4 acc[4][2];
    #pragma unroll
    for (int ti = 0; ti < 4; ti++)
      #pragma unroll
      for (int tj = 0; tj < 2; tj++){
        acc[ti][tj] = z4;
        #pragma unroll
        for (int kc = 0; kc < 2; kc++)
          acc[ti][tj] = __builtin_amdgcn_mfma_f32_16x16x32_bf16(aw[ti][kc], bx[tj][kc], acc[ti][tj], 0, 0, 0);
      }
    float adj[4][4];
    #pragma unroll
    for (int ti = 0; ti < 4; ti++)
      #pragma unroll
      for (int r = 0; r < 4; r++)
        adj[ti][r] = bk[ti*16 + lg*4 + r] - km[b*64 + ti*16 + lg*4 + r];
    float up[2] = {0.f, 0.f};
    #pragma unroll
    for (int ti = 0; ti < 4; ti++)
      #pragma unroll
      for (int tj = 0; tj < 2; tj++){
        float v0 = acc[ti][tj][0] + adj[ti][0];
        float v1 = acc[ti][tj][1] + adj[ti][1];
        float v2 = acc[ti][tj][2] + adj[ti][2];
        float v3 = acc[ti][tj][3] + adj[ti][3];
        up[tj] += qmv[ti][0]*v0 + qmv[ti][1]*v1 + qmv[ti][2]*v2 + qmv[ti][3]*v3;
        uint32_t p0 = ((uint32_t)(uint16_t)f2bf(v1) << 16) | (uint16_t)f2bf(v0);
        uint32_t p1 = ((uint32_t)(uint16_t)f2bf(v3) << 16) | (uint16_t)f2bf(v2);
        uint32_t* kr = (uint32_t*)(Kb + (size_t)ncol[tj]*64);
        kr[ti*8 + lg*2]     = p0;
        kr[ti*8 + lg*2 + 1] = p1;
      }
    #pragma unroll
    for (int tj = 0; tj < 2; tj++){
      float s = up[tj];
      s += __shfl_xor(s, 16);
      s += __shfl_xor(s, 32);
      if (lg == 0) u[(size_t)b*N_PIX + ncol[tj]] = s;
    }
  }

  // ---------- V ----------
  {
    short8 aw[4][2];
    #pragma unroll
    for (int ti = 0; ti < 4; ti++)
      #pragma unroll
      for (int kc = 0; kc < 2; kc++){
        const float* wr = wv + (ti*16 + lr)*64 + kc*32 + lg*8;
        short8 t;
        #pragma unroll
        for (int j = 0; j < 8; j++) t[j] = f2bf(wr[j]);
        aw[ti][kc] = t;
      }
    f32x4 acc[4][2];
    #pragma unroll
    for (int ti = 0; ti < 4; ti++)
      #pragma unroll
      for (int tj = 0; tj < 2; tj++){
        acc[ti][tj] = z4;
        #pragma unroll
        for (int kc = 0; kc < 2; kc++)
          acc[ti][tj] = __builtin_amdgcn_mfma_f32_16x16x32_bf16(aw[ti][kc], bx[tj][kc], acc[ti][tj], 0, 0, 0);
      }
    #pragma unroll
    for (int ti = 0; ti < 4; ti++)
      #pragma unroll
      for (int tj = 0; tj < 2; tj++){
        #pragma unroll
        for (int r = 0; r < 4; r++){
          float v = acc[ti][tj][r] + bv[ti*16 + lg*4 + r];
          Vb[(size_t)(ti*16 + lg*4 + r) * N_PIX + ncol[tj]] = f2bf(v);
        }
      }
  }
}

// ---------------- K2: unary softmax + out_unary ----------------
__global__ __launch_bounds__(256) void k_unary(const float* __restrict__ u, const short* __restrict__ V,
                                               float* __restrict__ ou){
  int b = blockIdx.x >> 6, c = blockIdx.x & 63;
  int tid = threadIdx.x, w = tid >> 6, l = tid & 63;
  const float* ub = u + (size_t)b * N_PIX;
  float mx = -1e30f;
  #pragma unroll
  for (int i = 0; i < 16; i++) mx = fmaxf(mx, ub[tid + 256*i]);
  mx = wredMax(mx);
  __shared__ float redm[4];
  if (l == 0) redm[w] = mx;
  __syncthreads();
  mx = fmaxf(fmaxf(redm[0], redm[1]), fmaxf(redm[2], redm[3]));
  const short* Vr = V + ((size_t)b*64 + c) * N_PIX;
  float ps = 0.f, vs = 0.f;
  #pragma unroll
  for (int i = 0; i < 16; i++){
    int m = tid + 256*i;
    float p = exp2f((ub[m] - mx) * LOG2E);
    ps += p;
    vs += p * bf2f(Vr[m]);
  }
  ps = wredSum(ps); vs = wredSum(vs);
  __shared__ float r1[4], r2[4];
  if (l == 0){ r1[w] = ps; r2[w] = vs; }
  __syncthreads();
  if (tid == 0) ou[b*64 + c] = (r2[0]+r2[1]+r2[2]+r2[3]) / (r1[0]+r1[1]+r1[2]+r1[3]);
}

// ---------------- K3: flash attention + epilogue ----------------
__global__ __launch_bounds__(256, 2) void k_attn(
    const short* __restrict__ Q, const short* __restrict__ K, const short* __restrict__ V,
    const float* __restrict__ ou, const float* __restrict__ x, float* __restrict__ out)
{
  int b  = blockIdx.x >> 6;
  int q0 = (blockIdx.x & 63) << 6;
  int tid = threadIdx.x;
  int w = tid >> 6, l = tid & 63, lr = l & 15, lg = l >> 4;

  __shared__ short Pbuf[4][64][40];    // per-wave P transpose buffer (padded)
  __shared__ short Opart[4][64][66];   // per-wave partial O (bf16, padded)
  __shared__ float lW[4][64];          // per-wave partial row sums

  const short* Qb = Q + (size_t)b * N_PIX * 64;
  const short* Kb = K + (size_t)b * N_PIX * 64;
  const short* Vb = V + (size_t)b * 64 * N_PIX;

  short8 aq[4][2];
  #pragma unroll
  for (int qt = 0; qt < 4; qt++)
    #pragma unroll
    for (int kc = 0; kc < 2; kc++)
      aq[qt][kc] = *(const short8*)(Qb + (size_t)(q0 + qt*16 + lr)*64 + kc*32 + lg*8);

  f32x4 acc[4][4];
  float rs[4][4];
  const f32x4 z4 = {0.f, 0.f, 0.f, 0.f};
  #pragma unroll
  for (int qt = 0; qt < 4; qt++)
    #pragma unroll
    for (int f = 0; f < 4; f++){
      acc[qt][f] = z4;
      rs[qt][f] = 0.f;
    }

  int kbase = w << 10;   // each wave owns 1024 keys

  for (int it = 0; it < 32; ++it){
    int kb = kbase + (it << 5);
    const short* krow0 = Kb + (size_t)(kb + lr)*64 + lg*8;
    const short* krow1 = krow0 + 16*64;
    short8 bk00 = *(const short8*)(krow0);
    short8 bk01 = *(const short8*)(krow0 + 32);
    short8 bk10 = *(const short8*)(krow1);
    short8 bk11 = *(const short8*)(krow1 + 32);
    short8 bv[4];
    #pragma unroll
    for (int f = 0; f < 4; f++)
      bv[f] = *(const short8*)(Vb + (size_t)(f*16 + lr)*N_PIX + kb + lg*8);

    #pragma unroll
    for (int qt = 0; qt < 4; qt++){
      f32x4 s0 = __builtin_amdgcn_mfma_f32_16x16x32_bf16(aq[qt][0], bk00, z4, 0, 0, 0);
      s0 = __builtin_amdgcn_mfma_f32_16x16x32_bf16(aq[qt][1], bk01, s0, 0, 0, 0);
      f32x4 s1 = __builtin_amdgcn_mfma_f32_16x16x32_bf16(aq[qt][0], bk10, z4, 0, 0, 0);
      s1 = __builtin_amdgcn_mfma_f32_16x16x32_bf16(aq[qt][1], bk11, s1, 0, 0, 0);
      #pragma unroll
      for (int r = 0; r < 4; r++){
        float p0 = exp2f(s0[r]);     // Q pre-scaled by log2(e)/8, fixed-max softmax
        float p1 = exp2f(s1[r]);
        rs[qt][r] += p0 + p1;
        int qrow = qt*16 + lg*4 + r;
        Pbuf[w][qrow][lr]      = f2bf(p0);
        Pbuf[w][qrow][16 + lr] = f2bf(p1);
      }
    }
    #pragma unroll
    for (int qt = 0; qt < 4; qt++){
      short8 ap = *(const short8*)(&Pbuf[w][qt*16 + lr][lg*8]);
      #pragma unroll
      for (int f = 0; f < 4; f++)
        acc[qt][f] = __builtin_amdgcn_mfma_f32_16x16x32_bf16(ap, bv[f], acc[qt][f], 0, 0, 0);
    }
  }

  // final cross-lane row-sum reduce (only once, at the end)
  #pragma unroll
  for (int qt = 0; qt < 4; qt++)
    #pragma unroll
    for (int r = 0; r < 4; r++){
      float v = rs[qt][r];
      v += __shfl_xor(v, 1); v += __shfl_xor(v, 2);
      v += __shfl_xor(v, 4); v += __shfl_xor(v, 8);
      rs[qt][r] = v;
    }
  if (lr == 0){
    #pragma unroll
    for (int qt = 0; qt < 4; qt++)
      #pragma unroll
      for (int r = 0; r < 4; r++)
        lW[w][qt*16 + lg*4 + r] = rs[qt][r];
  }
  #pragma unroll
  for (int qt = 0; qt < 4; qt++)
    #pragma unroll
    for (int f = 0; f < 4; f++)
      #pragma unroll
      for (int r = 0; r < 4; r++)
        Opart[w][qt*16 + lg*4 + r][f*16 + lr] = f2bf(acc[qt][f][r]);
  __syncthreads();

  const float* xb = x + (size_t)b * 64 * N_PIX;
  float* ob = out + (size_t)b * 64 * N_PIX;
  const float* oub = ou + b*64;
  #pragma unroll
  for (int i = 0; i < 16; i++){
    int idx = i*256 + tid;
    int c = idx >> 6, q = idx & 63;
    float os = bf2f(Opart[0][q][c]) + bf2f(Opart[1][q][c])
             + bf2f(Opart[2][q][c]) + bf2f(Opart[3][q][c]);
    float lt = lW[0][q] + lW[1][q] + lW[2][q] + lW[3][q];
    size_t gi = (size_t)c * N_PIX + q0 + q;
    ob[gi] = xb[gi] + os / lt + oub[c];
  }
}

extern "C" void kernel_launch(void* const* d_in, const int* in_sizes, int n_in,
                              void* d_out, int out_size, void* d_ws, size_t ws_size,
                              hipStream_t stream)
{
  (void)in_sizes; (void)n_in; (void)out_size; (void)ws_size;
  const float* x  = (const float*)d_in[0];
  const float* wq = (const float*)d_in[1];
  const float* bq = (const float*)d_in[2];
  const float* wk = (const float*)d_in[3];
  const float* bk = (const float*)d_in[4];
  const float* wv = (const float*)d_in[5];
  const float* bv = (const float*)d_in[6];
  float* out = (float*)d_out;

  char* ws = (char*)d_ws;
  short* Q  = (short*)(ws);                 // 8*4096*64 bf16 = 4 MiB
  short* K  = (short*)(ws + 4194304);       // 4 MiB
  short* V  = (short*)(ws + 8388608);       // 4 MiB
  float* u  = (float*)(ws + 12582912);      // 8*4096 f32 = 128 KiB
  float* xm = (float*)(ws + 12713984);      // 8*64 f32
  float* qm = (float*)(ws + 12716032);
  float* km = (float*)(ws + 12718080);
  float* ou = (float*)(ws + 12720128);

  k_xmean<<<dim3(512), dim3(256), 0, stream>>>(x, xm);
  k_means<<<dim3(8), dim3(64), 0, stream>>>(wq, bq, wk, bk, xm, qm, km);
  k_qkv<<<dim3(256), dim3(256), 0, stream>>>(x, wq, bq, wk, bk, wv, bv, qm, km, Q, K, V, u);
  k_unary<<<dim3(512), dim3(256), 0, stream>>>(u, V, ou);
  k_attn<<<dim3(512), dim3(256), 0, stream>>>(Q, K, V, ou, x, out);
}